// Round 12
// baseline (324.035 us; speedup 1.0000x reference)
//
#include <hip/hip_runtime.h>
#include <math.h>

#define NPROT 50000
#define NCLS  5000
#define DIMP  1280
#define DIMC  256
#define SCAN_N (NCLS + NPROT)
#define KSTEPS (DIMP/32)          // 40

#define P1B  ((NPROT+63)/64)      // 782 gemm_p1 blocks (64x256 tile, 8 waves)
#define C1BY ((NCLS+63)/64)       // 79
#define C1B  (4*C1BY)             // 316 gemm64 blocks

typedef float4 f4;
typedef __attribute__((ext_vector_type(8))) short short8;
typedef __attribute__((ext_vector_type(4))) float f32x4;

// ---------- helpers ----------
__device__ __forceinline__ unsigned short f2bf(float f){   // RNE
    unsigned u = __float_as_uint(f);
    u += 0x7FFFu + ((u >> 16) & 1u);
    return (unsigned short)(u >> 16);
}
__device__ __forceinline__ float bf2f(unsigned short b){
    return __uint_as_float(((unsigned)b) << 16);
}
__device__ __forceinline__ void gload_lds16(const void* g, void* l){
    __builtin_amdgcn_global_load_lds((const __attribute__((address_space(1))) void*)g,
                                     (__attribute__((address_space(3))) void*)l, 16, 0, 0);
}
__device__ __forceinline__ int OFFV(const int* __restrict__ offv, const int* __restrict__ part, int v){
    return offv[v] + part[v>>10];
}

// ---------- mega kernel (512 thr, 8 waves): [gemm_p1 64x256 | gemm64 C1 | csr_fill] ----------
__global__ __launch_bounds__(512) void mega1(const float* __restrict__ Af,          // x_p
                                             const unsigned short* __restrict__ BtP,
                                             unsigned short* __restrict__ P1,
                                             const float* __restrict__ Ac,          // x_c
                                             const float* __restrict__ WcatC,
                                             unsigned short* __restrict__ C1,       // bf16 out
                                             const int* __restrict__ src, const int* __restrict__ dst,
                                             const int* __restrict__ offv, const int* __restrict__ part,
                                             int* __restrict__ cur, int* __restrict__ adj, int E){
    __shared__ __align__(16) unsigned char smem[40*1024];   // 40 KB -> 4 blocks/CU (32 waves)
    const int blk = blockIdx.x;
    const int tid = threadIdx.x;

    if(blk < P1B){
        // ---- gemm_p1: 64x256 tile; 8 waves x 32-col strip; A reg-staged, B gload_lds, dbuf ----
        unsigned char* As = smem;               // 2 x 4 KB  (64x32 bf16, swizzled)
        unsigned char* Bs = smem + 8*1024;      // 2 x 16 KB (256x32 bf16, swizzled)
        const int lane = tid & 63;
        const int w    = tid >> 6;              // 0..7: col strip w*32
        const int row0 = blk * 64;
        const int kg = lane >> 4, fr = lane & 15;

        // A staging: thread -> row ar_=tid>>3 (0..63), 16B-f32 chunk ac8=tid&7 (of 8 per row)
        const int ar_ = tid >> 3;
        const int ac8 = tid & 7;
        const int asrow = min(row0 + ar_, NPROT-1);
        const float* aG = Af + (size_t)asrow*DIMP + ac8*4;
        // bf16 dest: row 64B; 16B slot s=ac8>>1 swizzled, 8B half h=ac8&1
        const int awoff = ar_*64 + (((ac8>>1) ^ ((ar_>>1)&3)) << 4) + (ac8&1)*8;

        f32x4 acc[4][2] = {};
        f4 va;

        auto STAGEB = [&](int buf, int k0){
            #pragma unroll
            for(int i=0;i<2;i++){
                int c  = i*512 + tid;
                int r  = c >> 2, cc = c & 3;
                int scc = cc ^ ((r>>1) & 3);
                gload_lds16((const void*)(BtP + (size_t)r*DIMP + k0 + scc*8),
                            (void*)(Bs + buf*16384 + (i*512 + tid)*16));
            }
        };
        auto WRITEA = [&](int buf){
            ushort4 u4;
            u4.x=f2bf(va.x); u4.y=f2bf(va.y); u4.z=f2bf(va.z); u4.w=f2bf(va.w);
            *(ushort4*)(As + buf*4096 + awoff) = u4;
        };

        // prologue: stage tile 0
        va = *(const f4*)(aG + 0);
        STAGEB(0, 0);
        WRITEA(0);
        __syncthreads();

        for(int t=0; t<KSTEPS; ++t){
            const int cb = t & 1;
            if(t+1 < KSTEPS){
                va = *(const f4*)(aG + (t+1)*32);       // issue early: in flight during MFMA
                STAGEB(cb^1, (t+1)*32);
            }

            const unsigned char* Ab = As + cb*4096;
            const unsigned char* Bb = Bs + cb*16384;
            short8 aF[4], bF[2];
            #pragma unroll
            for(int m=0;m<4;m++){
                int r = m*16 + fr;
                aF[m] = *(const short8*)(Ab + r*64 + ((kg ^ ((r>>1)&3))<<4));
            }
            #pragma unroll
            for(int n=0;n<2;n++){
                int r = w*32 + n*16 + fr;
                bF[n] = *(const short8*)(Bb + r*64 + ((kg ^ ((r>>1)&3))<<4));
            }
            #pragma unroll
            for(int m=0;m<4;m++)
            #pragma unroll
            for(int n=0;n<2;n++)
                acc[m][n] = __builtin_amdgcn_mfma_f32_16x16x32_bf16(aF[m], bF[n], acc[m][n], 0, 0, 0);

            if(t+1 < KSTEPS) WRITEA(cb^1);      // write-late: cvt+ds_write after MFMA issue
            __syncthreads();
        }

        #pragma unroll
        for(int m=0;m<4;m++)
        #pragma unroll
        for(int r=0;r<4;r++){
            int row = row0 + m*16 + kg*4 + r;
            if(row < NPROT){
                #pragma unroll
                for(int n=0;n<2;n++)
                    P1[(size_t)row*256 + w*32 + n*16 + fr] = f2bf(acc[m][n][r]);
            }
        }
    } else if(blk < P1B + C1B){
        // ---- gemm64: C1[64,64] tile = x_c @ WcatC (f32 math, bf16 store); tid<256 active ----
        float (*As64)[68] = (float(*)[68])smem;
        float (*Bs64)[64] = (float(*)[64])(smem + 16*68*4);
        const int bi = blk - P1B;
        const int row0 = (bi >> 2) * 64;
        const int col0 = (bi & 3) * 64;
        const bool act = tid < 256;
        const int ty = tid >> 4;
        const int tx = tid & 15;
        const int m  = tid >> 2;
        const int kq = (tid & 3) << 2;
        const int kb = tid >> 4;
        const int c4 = (tid & 15) << 2;

        float acc[4][4];
        #pragma unroll
        for(int i=0;i<4;i++)
        #pragma unroll
            for(int j=0;j<4;j++) acc[i][j]=0.f;

        const bool arow_ok = act && (row0 + m) < NCLS;
        const float* Abase = Ac + (size_t)(row0 + min(m,255)) * DIMC + kq;
        const float* Bbase = WcatC + col0 + c4 + (size_t)min(kb,15) * 256;

        for(int k0 = 0; k0 < DIMC; k0 += 16){
            if(act){
                f4 av;
                if(arow_ok) av = *(const f4*)(Abase + k0);
                else        av = make_float4(0.f,0.f,0.f,0.f);
                As64[kq+0][m]=av.x; As64[kq+1][m]=av.y; As64[kq+2][m]=av.z; As64[kq+3][m]=av.w;
                *(f4*)&Bs64[kb][c4] = *(const f4*)(Bbase + (size_t)k0 * 256);
            }
            __syncthreads();
            if(act){
                #pragma unroll
                for(int kk=0;kk<16;kk++){
                    f4 a = *(const f4*)&As64[kk][ty<<2];
                    f4 b = *(const f4*)&Bs64[kk][tx<<2];
                    float ar[4]={a.x,a.y,a.z,a.w};
                    float br[4]={b.x,b.y,b.z,b.w};
                    #pragma unroll
                    for(int i=0;i<4;i++)
                    #pragma unroll
                        for(int j=0;j<4;j++) acc[i][j] += ar[i]*br[j];
                }
            }
            __syncthreads();
        }
        if(act){
            #pragma unroll
            for(int i=0;i<4;i++){
                int r = row0 + (ty<<2) + i;
                if(r < NCLS){
                    ushort4 v;
                    v.x=f2bf(acc[i][0]); v.y=f2bf(acc[i][1]);
                    v.z=f2bf(acc[i][2]); v.w=f2bf(acc[i][3]);
                    *(ushort4*)&C1[(size_t)r*256 + col0 + (tx<<2)] = v;
                }
            }
        }
    } else {
        // ---- csr_fill (512 thr/block) ----
        int e = (blk - P1B - C1B)*512 + tid;
        if(e < E){
            int s = src[e], d = dst[e];
            int pc = atomicAdd(&cur[d],1);        adj[OFFV(offv,part,d)+pc] = s;
            int pp = atomicAdd(&cur[NCLS+s],1);   adj[OFFV(offv,part,NCLS+s)+pp] = d;
        }
    }
}

// ---------- hs GEMM (both node types) + fused att (x==0 blocks) ----------
#define NPB ((NPROT+127)/128)
#define NCB ((NCLS+127)/128)
__global__ __launch_bounds__(256) void gemm_hs(const unsigned short* __restrict__ Ap,
                                               const unsigned short* __restrict__ Ac,
                                               const unsigned short* __restrict__ Btp,
                                               const unsigned short* __restrict__ Btc,
                                               const float* __restrict__ projP,
                                               const float* __restrict__ projC,
                                               unsigned short* __restrict__ Cp,
                                               unsigned short* __restrict__ Cc,
                                               float* __restrict__ attP,
                                               float* __restrict__ attC){
    const bool cls = (int)blockIdx.y >= NPB;
    const unsigned short* A  = cls ? Ac : Ap;
    const unsigned short* Bt = cls ? Btc : Btp;
    unsigned short* C = cls ? Cc : Cp;
    const int M = cls ? NCLS : NPROT;
    const int row0 = (cls ? blockIdx.y - NPB : blockIdx.y) * 128;
    const int col0 = blockIdx.x * 128;

    __shared__ __align__(16) unsigned char As[128*32*2];
    __shared__ __align__(16) unsigned char Bs[128*32*2];
    __shared__ float projS[1024];
    const int tid  = threadIdx.x;
    const int lane = tid & 63;
    const int w    = tid >> 6;
    const int wm   = w >> 1, wn = w & 1;
    const int kg = lane >> 4, fr = lane & 15;

    f32x4 acc[4][4] = {};

    for(int k0 = 0; k0 < 128; k0 += 32){
        #pragma unroll
        for(int i=0;i<2;i++){
            int c  = i*256 + w*64 + lane;
            int r  = c >> 2, cc = c & 3;
            int scc = cc ^ ((r>>1) & 3);
            int srow = min(row0 + r, M-1);
            gload_lds16((const void*)(A + (size_t)srow*128 + k0 + scc*8),
                        (void*)(As + (i*256 + w*64)*16));
        }
        #pragma unroll
        for(int i=0;i<2;i++){
            int c  = i*256 + w*64 + lane;
            int r  = c >> 2, cc = c & 3;
            int scc = cc ^ ((r>>1) & 3);
            gload_lds16((const void*)(Bt + (size_t)(col0 + r)*128 + k0 + scc*8),
                        (void*)(Bs + (i*256 + w*64)*16));
        }
        __syncthreads();

        short8 aF[4], bF[4];
        #pragma unroll
        for(int m=0;m<4;m++){
            int r = wm*64 + m*16 + fr;
            int b0 = (r*64 + kg*16) ^ (((r>>1)&3)<<4);
            aF[m] = *(const short8*)(As + b0);
        }
        #pragma unroll
        for(int n=0;n<4;n++){
            int r = wn*64 + n*16 + fr;
            int b0 = (r*64 + kg*16) ^ (((r>>1)&3)<<4);
            bF[n] = *(const short8*)(Bs + b0);
        }
        #pragma unroll
        for(int m=0;m<4;m++)
        #pragma unroll
        for(int n=0;n<4;n++)
            acc[m][n] = __builtin_amdgcn_mfma_f32_16x16x32_bf16(aF[m], bF[n], acc[m][n], 0, 0, 0);
        __syncthreads();
    }

    #pragma unroll
    for(int m=0;m<4;m++)
    #pragma unroll
    for(int r=0;r<4;r++){
        int row = row0 + wm*64 + m*16 + kg*4 + r;
        if(row < M){
            #pragma unroll
            for(int n=0;n<4;n++)
                C[(size_t)row*512 + col0 + wn*64 + n*16 + fr] = f2bf(acc[m][n][r]);
        }
    }

    // fused att: only x==0 blocks; att[row,0:8] = h[row,:] @ proj[128,8]
    if(blockIdx.x == 0){
        const float* proj = cls ? projC : projP;
        float* att = cls ? attC : attP;
        for(int i=tid;i<1024;i+=256) projS[i] = proj[i];
        __syncthreads();
        int ri = tid >> 1, cb = (tid & 1)*4;
        int row = row0 + ri;
        if(row < M){
            const unsigned short* ar = A + (size_t)row*128;
            float s0=0.f,s1=0.f,s2=0.f,s3=0.f;
            #pragma unroll
            for(int kk=0;kk<16;kk++){
                short8 a8 = *(const short8*)(ar + kk*8);
                #pragma unroll
                for(int q=0;q<8;q++){
                    float av = bf2f((unsigned short)a8[q]);
                    const float* pr = &projS[(kk*8+q)*8 + cb];
                    s0 += av*pr[0]; s1 += av*pr[1]; s2 += av*pr[2]; s3 += av*pr[3];
                }
            }
            f4 o = make_float4(s0,s1,s2,s3);
            *(f4*)&att[(size_t)row*8 + cb] = o;
        }
    }
}

// ---------- merged setup: prep_weights ∪ folds ∪ deg ----------
__global__ void setup(const float* __restrict__ Wl_pc, const float* __restrict__ Wr_cp,
                      const float* __restrict__ Wl_cp, const float* __restrict__ Wr_pc,
                      const float* __restrict__ pcWs, const float* __restrict__ pcAs,
                      const float* __restrict__ pcWd, const float* __restrict__ pcAd,
                      const float* __restrict__ cpWs, const float* __restrict__ cpAs,
                      const float* __restrict__ cpWd, const float* __restrict__ cpAd,
                      const float* __restrict__ lpW, const float* __restrict__ lpb,
                      const float* __restrict__ lcW, const float* __restrict__ lcb,
                      const float* __restrict__ linkW,
                      const int* __restrict__ src, const int* __restrict__ dst,
                      unsigned short* __restrict__ BtP, float* __restrict__ WcatC,
                      unsigned short* __restrict__ BtSp, unsigned short* __restrict__ BtSc,
                      float* __restrict__ projP, float* __restrict__ projC,
                      float* __restrict__ w_p, float* __restrict__ w_c,
                      float* __restrict__ cpc,
                      int* __restrict__ deg, int E){
    int blk = blockIdx.x, tid = threadIdx.x;
    if(blk < 2048){
        int t = blk*256 + tid;
        if(t < 327680){
            int n = t / 1280, k = t % 1280;
            float v = (n<128) ? Wl_pc[(size_t)k*128+n] : Wr_cp[(size_t)k*128+n-128];
            BtP[t] = f2bf(v);
        } else if(t < 393216){
            int i = t - 327680; int k = i>>8, j = i&255;
            WcatC[i] = (j<128) ? Wl_cp[(size_t)k*128+j] : Wr_pc[(size_t)k*128+j-128];
        } else if(t < 458752){
            int i = t - 393216; int n = i>>7, k = i&127;
            BtSp[i] = f2bf(pcWs[(size_t)k*512+n]);
        } else {
            int i = t - 458752; int n = i>>7, k = i&127;
            BtSc[i] = f2bf(cpWs[(size_t)k*512+n]);
        }
    } else if(blk < 2056){
        int sec = (blk-2048) >> 1;
        int t = ((blk-2048) & 1)*256 + tid;
        const float *W, *a; float* proj; int colbase;
        if(sec==0){ W=pcWs; a=pcAs; proj=projP; colbase=0; }
        else if(sec==1){ W=cpWd; a=cpAd; proj=projP; colbase=4; }
        else if(sec==2){ W=pcWd; a=pcAd; proj=projC; colbase=0; }
        else { W=cpWs; a=cpAs; proj=projC; colbase=4; }
        int k = t >> 2, h = t & 3;
        const float* w = W + (size_t)k*512 + h*128;
        const float* av = a + h*128;
        float s=0.f;
        for(int c=0;c<128;c++) s += w[c]*av[c];
        proj[k*8 + colbase + h] = s;
    } else if(blk == 2056){
        if(tid < 128){
            float s=0.f;
            for(int o=0;o<128;o++) s += lpW[(size_t)tid*128+o]*linkW[o];
            w_p[tid]=s;
        } else {
            int j=tid-128;
            float s=0.f;
            for(int o=0;o<128;o++) s += lcW[(size_t)j*128+o]*linkW[128+o];
            w_c[j]=s;
        }
        if(tid==0){ float s=0.f; for(int o=0;o<128;o++) s+=lpb[o]*linkW[o];      cpc[0]=s; }
        if(tid==1){ float s=0.f; for(int o=0;o<128;o++) s+=lcb[o]*linkW[128+o];  cpc[1]=s; }
    } else {
        int e = (blk-2057)*256 + tid;
        if(e < E){
            atomicAdd(&deg[dst[e]],1);
            atomicAdd(&deg[NCLS + src[e]],1);
        }
    }
}

// ---------- hierarchical exclusive scan ----------
__global__ __launch_bounds__(1024) void scan1(const int* __restrict__ in, int* __restrict__ out,
                                              int* __restrict__ part, int n){
    __shared__ int buf[1024];
    int tid = threadIdx.x;
    int g = blockIdx.x*1024 + tid;
    int v = (g<n) ? in[g] : 0;
    buf[tid] = v;
    __syncthreads();
    for(int o=1;o<1024;o<<=1){
        int t = (tid>=o) ? buf[tid-o] : 0;
        __syncthreads();
        buf[tid] += t;
        __syncthreads();
    }
    if(g<n) out[g] = buf[tid] - v;
    if(tid==1023) part[blockIdx.x] = buf[1023];
}
__global__ __launch_bounds__(64) void scan2(int* __restrict__ part, int nb,
                                            int* __restrict__ offv, int n){
    int tid = threadIdx.x;
    int orig = (tid<nb) ? part[tid] : 0;
    int v = orig;
    #pragma unroll
    for(int o=1;o<64;o<<=1){
        int t = __shfl_up(v, o);
        if(tid>=o) v += t;
    }
    int total = __shfl(v, nb-1);
    if(tid<nb) part[tid] = v - orig;
    if(tid == (n>>10)) offv[n] = total - (v - orig);
}

// ---------- merged SAGE (both types; C1 bf16) ----------
__global__ __launch_bounds__(256) void sage_all(const int* __restrict__ offv, const int* __restrict__ part,
                                                const int* __restrict__ adj,
                                                const unsigned short* __restrict__ P1,
                                                const unsigned short* __restrict__ C1,
                                                const float* __restrict__ bl_pc, const float* __restrict__ bl_cp,
                                                unsigned short* __restrict__ h_c, unsigned short* __restrict__ h_p){
    int v = blockIdx.x*4 + (threadIdx.x>>6);
    int l = threadIdx.x & 63;
    if(v >= SCAN_N) return;
    int b = OFFV(offv,part,v), deg = OFFV(offv,part,v+1)-b;
    float a0=0.f, a1=0.f;
    float inv = 1.f/(float)max(deg,1);
    if(v < NCLS){
        #pragma unroll 4
        for(int i=0;i<deg;i++){
            int s = adj[b+i];
            ushort2 w = *((const ushort2*)P1 + (size_t)s*128 + l);
            a0 += bf2f(w.x); a1 += bf2f(w.y);
        }
        ushort2 sv = *((const ushort2*)C1 + (size_t)v*128 + 64 + l);
        float h0 = fmaxf(a0*inv + bl_pc[2*l]   + bf2f(sv.x), 0.f);
        float h1 = fmaxf(a1*inv + bl_pc[2*l+1] + bf2f(sv.y), 0.f);
        ushort2 o; o.x=f2bf(h0); o.y=f2bf(h1);
        *((ushort2*)h_c + (size_t)v*64 + l) = o;
    } else {
        int m = v - NCLS;
        #pragma unroll 4
        for(int i=0;i<deg;i++){
            int d = adj[b+i];
            ushort2 w = *((const ushort2*)C1 + (size_t)d*128 + l);
            a0 += bf2f(w.x); a1 += bf2f(w.y);
        }
        ushort2 sv = *((const ushort2*)P1 + (size_t)m*128 + 64 + l);
        float h0 = fmaxf(a0*inv + bl_cp[2*l]   + bf2f(sv.x), 0.f);
        float h1 = fmaxf(a1*inv + bl_cp[2*l+1] + bf2f(sv.y), 0.f);
        ushort2 o; o.x=f2bf(h0); o.y=f2bf(h1);
        *((ushort2*)h_p + (size_t)m*64 + l) = o;
    }
}

// ---------- fused GAT: thread j = head (j>>5) x 4 channels (4*(j&31)) ----------
__global__ __launch_bounds__(128) void gat_all(const int* __restrict__ offv, const int* __restrict__ part,
                                               const int* __restrict__ adj,
                                               const float* __restrict__ attP, const float* __restrict__ attC,
                                               const unsigned short* __restrict__ hs_p,
                                               const unsigned short* __restrict__ hs_c,
                                               const float* __restrict__ gb_pc, const float* __restrict__ gb_cp,
                                               const float* __restrict__ w_c, const float* __restrict__ w_p,
                                               const float* __restrict__ cpc,
                                               float* __restrict__ u_c, float* __restrict__ u_p){
    __shared__ float ald[4];
    __shared__ int   adjS[32];
    __shared__ float eeS[32*4];
    __shared__ float den8[8];
    __shared__ f4    red4[32];

    int n = blockIdx.x;
    const bool cls = n < NCLS;
    const int node = cls ? n : n - NCLS;
    const float* attS = cls ? attP : attC;
    const float* attD = cls ? attC : attP;
    const int abase = cls ? 0 : 4;
    const unsigned short* hs = cls ? hs_p : hs_c;
    const float* gb = cls ? gb_pc : gb_cp;
    const float* wv = cls ? w_c : w_p;
    float* u = cls ? u_c : u_p;
    const int cidx = cls ? 1 : 0;

    int j = threadIdx.x;
    const int hh = j >> 5;          // head
    const int q  = j & 31;          // channel group: channels 4q..4q+3
    int b = OFFV(offv,part,n), deg = OFFV(offv,part,n+1)-b;
    if(j < 4) ald[j] = attD[(size_t)node*8 + abase + j];

    float a0=0.f, a1=0.f, a2=0.f, a3=0.f;
    float denP = 0.f;

    for(int base=0; base<deg; base+=32){
        int cnt = min(32, deg-base);
        if(j < cnt) adjS[j] = adj[b+base+j];
        __syncthreads();
        if(j < cnt*4){
            int i = j>>2, h = j&3;
            int s = adjS[i];
            float e = attS[(size_t)s*8 + abase + h] + ald[h];
            e = e > 0.f ? e : 0.2f*e;
            float ee = __expf(e);
            eeS[j] = ee;
            denP += ee;
        }
        __syncthreads();
        #pragma unroll 4
        for(int ii=0; ii<cnt; ii++){
            int s = adjS[ii];
            float ee = eeS[ii*4 + hh];
            ushort4 v = *(const ushort4*)(hs + (size_t)s*512 + hh*128 + q*4);
            a0 += ee*bf2f(v.x); a1 += ee*bf2f(v.y);
            a2 += ee*bf2f(v.z); a3 += ee*bf2f(v.w);
        }
        __syncthreads();
    }

    // per-head denominators: thread j contributed to head (j&3); shfl-reduce per wave
    float dp = denP;
    dp += __shfl_xor(dp, 4);
    dp += __shfl_xor(dp, 8);
    dp += __shfl_xor(dp, 16);
    dp += __shfl_xor(dp, 32);
    if((j & 63) < 4) den8[(j>>6)*4 + (j&3)] = dp;
    __syncthreads();

    float den_h = den8[hh] + den8[4+hh];
    float inv = (deg > 0) ? 0.25f/den_h : 0.f;
    a0 *= inv; a1 *= inv; a2 *= inv; a3 *= inv;

    // head-mean: pair-reduce within wave (head0+1 / head2+3), then cross-wave via LDS
    a0 += __shfl_xor(a0, 32); a1 += __shfl_xor(a1, 32);
    a2 += __shfl_xor(a2, 32); a3 += __shfl_xor(a3, 32);
    if(j >= 64 && j < 96) red4[q] = make_float4(a0,a1,a2,a3);
    __syncthreads();
    float val = 0.f;
    if(j < 32){
        f4 r = red4[q];
        float t0 = a0 + r.x, t1 = a1 + r.y, t2 = a2 + r.z, t3 = a3 + r.w;
        const float* gbq = gb + q*4;
        const float* wvq = wv + q*4;
        val = fmaxf(t0 + gbq[0], 0.f)*wvq[0]
            + fmaxf(t1 + gbq[1], 0.f)*wvq[1]
            + fmaxf(t2 + gbq[2], 0.f)*wvq[2]
            + fmaxf(t3 + gbq[3], 0.f)*wvq[3];
    }
    #pragma unroll
    for(int o=16;o;o>>=1) val += __shfl_down(val, o);
    if(j == 0) u[node] = val + cpc[cidx];
}

__global__ void link_out(const int* __restrict__ els, const int* __restrict__ eld,
                         const float* __restrict__ u_p, const float* __restrict__ u_c,
                         const float* __restrict__ linkb, float* __restrict__ out, int EL){
    int i = blockIdx.x*256 + threadIdx.x;
    if(i >= EL) return;
    float x = u_p[els[i]] + u_c[eld[i]] + linkb[0];
    out[i] = 1.f/(1.f + __expf(-x));
}

// ---------- host ----------
extern "C" void kernel_launch(void* const* d_in, const int* in_sizes, int n_in,
                              void* d_out, int out_size, void* d_ws, size_t ws_size,
                              hipStream_t stream){
    const float* x_p  = (const float*)d_in[0];
    const float* x_c  = (const float*)d_in[1];
    const int*   src  = (const int*)d_in[2];
    const int*   dst  = (const int*)d_in[3];
    const int*   els  = (const int*)d_in[4];
    const int*   eld  = (const int*)d_in[5];
    const float* sage_pc_Wl = (const float*)d_in[6];
    const float* sage_pc_bl = (const float*)d_in[7];
    const float* sage_pc_Wr = (const float*)d_in[8];
    const float* sage_cp_Wl = (const float*)d_in[9];
    const float* sage_cp_bl = (const float*)d_in[10];
    const float* sage_cp_Wr = (const float*)d_in[11];
    const float* gat_pc_Wsrc = (const float*)d_in[12];
    const float* gat_pc_Wdst = (const float*)d_in[13];
    const float* gat_pc_asrc = (const float*)d_in[14];
    const float* gat_pc_adst = (const float*)d_in[15];
    const float* gat_pc_b    = (const float*)d_in[16];
    const float* gat_cp_Wsrc = (const float*)d_in[17];
    const float* gat_cp_Wdst = (const float*)d_in[18];
    const float* gat_cp_asrc = (const float*)d_in[19];
    const float* gat_cp_adst = (const float*)d_in[20];
    const float* gat_cp_b    = (const float*)d_in[21];
    const float* lin_p_W = (const float*)d_in[22];
    const float* lin_p_b = (const float*)d_in[23];
    const float* lin_c_W = (const float*)d_in[24];
    const float* lin_c_b = (const float*)d_in[25];
    const float* link_W  = (const float*)d_in[26];
    const float* link_b  = (const float*)d_in[27];

    const int E  = in_sizes[2];
    const int EL = in_sizes[4];

    float* ws = (float*)d_ws;
    size_t off = 0;
    auto alloc = [&](size_t n)->float*{ float* p = ws + off; off += (n + 3) & ~(size_t)3; return p; };

    unsigned short* BtP  = (unsigned short*)alloc((size_t)256*DIMP/2);
    float* WcatC = alloc((size_t)DIMC*256);
    unsigned short* BtSp = (unsigned short*)alloc((size_t)512*128/2);
    unsigned short* BtSc = (unsigned short*)alloc((size_t)512*128/2);
    unsigned short* P1   = (unsigned short*)alloc((size_t)NPROT*256/2);
    unsigned short* C1   = (unsigned short*)alloc((size_t)NCLS*256/2);
    unsigned short* h_p  = (unsigned short*)alloc((size_t)NPROT*128/2);
    unsigned short* h_c  = (unsigned short*)alloc((size_t)NCLS*128/2);
    unsigned short* hs_p = (unsigned short*)alloc((size_t)NPROT*512/2);
    unsigned short* hs_c = (unsigned short*)alloc((size_t)NCLS*512/2);
    float* attP  = alloc((size_t)NPROT*8);
    float* attC  = alloc((size_t)NCLS*8);
    float* projP = alloc(128*8);
    float* projC = alloc(128*8);
    float* w_p   = alloc(128);
    float* w_c   = alloc(128);
    float* cpc   = alloc(4);
    int* degcur = (int*)alloc((size_t)2*SCAN_N);   // deg | cur (one memset)
    int* deg = degcur;
    int* cur = degcur + SCAN_N;
    int* offv = (int*)alloc(SCAN_N+1);
    int* part = (int*)alloc(64);
    int* adj  = (int*)alloc((size_t)2*E);
    float* u_p = alloc(NPROT);
    float* u_c = alloc(NCLS);
    if(off*4 > ws_size) return;

    hipMemsetAsync(degcur, 0, (size_t)2*SCAN_N*4, stream);

    // --- setup: weight prep + folds + degree count ---
    setup<<<2057 + (E+255)/256, 256, 0, stream>>>(
        sage_pc_Wl, sage_cp_Wr, sage_cp_Wl, sage_pc_Wr,
        gat_pc_Wsrc, gat_pc_asrc, gat_pc_Wdst, gat_pc_adst,
        gat_cp_Wsrc, gat_cp_asrc, gat_cp_Wdst, gat_cp_adst,
        lin_p_W, lin_p_b, lin_c_W, lin_c_b, link_W,
        src, dst,
        BtP, WcatC, BtSp, BtSc, projP, projC, w_p, w_c, cpc, deg, E);

    // --- scan ---
    const int NB = (SCAN_N + 1023)/1024;
    scan1<<<NB,1024,0,stream>>>(deg, offv, part, SCAN_N);
    scan2<<<1,64,0,stream>>>(part, NB, offv, SCAN_N);

    // --- mega: gemm_p1(64x256, 8 waves, dbuf) | gemm64(C1 bf16) | csr_fill ---
    const int FILLB = (E+511)/512;
    mega1<<<P1B + C1B + FILLB, 512, 0, stream>>>(x_p, BtP, P1, x_c, WcatC, C1,
                                                 src, dst, offv, part, cur, adj, E);

    // --- SAGE ---
    sage_all<<<(SCAN_N+3)/4,256,0,stream>>>(offv, part, adj, P1, C1, sage_pc_bl, sage_cp_bl, h_c, h_p);

    // --- layer 2 GEMM (+ fused att) ---
    gemm_hs<<<dim3(4,NPB+NCB),256,0,stream>>>(h_p, h_c, BtSp, BtSc, projP, projC,
                                              hs_p, hs_c, attP, attC);

    // --- fused GAT + output head ---
    gat_all<<<SCAN_N,128,0,stream>>>(offv, part, adj, attP, attC, hs_p, hs_c,
                                     gat_pc_b, gat_cp_b, w_c, w_p, cpc, u_c, u_p);

    link_out<<<(EL+255)/256,256,0,stream>>>(els, eld, u_p, u_c, link_b, (float*)d_out, EL);
}

// Round 13
// 315.710 us; speedup vs baseline: 1.0264x; 1.0264x over previous
//
#include <hip/hip_runtime.h>
#include <math.h>

#define NPROT 50000
#define NCLS  5000
#define DIMP  1280
#define DIMC  256
#define SCAN_N (NCLS + NPROT)
#define KSTEPS (DIMP/32)          // 40

#define P1B  ((NPROT+127)/128)    // 391 gemm_p1 blocks (128x256 tile)
#define C1BY ((NCLS+63)/64)       // 79
#define C1B  (4*C1BY)             // 316 gemm64 blocks

typedef float4 f4;
typedef __attribute__((ext_vector_type(8))) short short8;
typedef __attribute__((ext_vector_type(4))) float f32x4;

// ---------- helpers ----------
__device__ __forceinline__ unsigned short f2bf(float f){   // RNE
    unsigned u = __float_as_uint(f);
    u += 0x7FFFu + ((u >> 16) & 1u);
    return (unsigned short)(u >> 16);
}
__device__ __forceinline__ float bf2f(unsigned short b){
    return __uint_as_float(((unsigned)b) << 16);
}
__device__ __forceinline__ void gload_lds16(const void* g, void* l){
    __builtin_amdgcn_global_load_lds((const __attribute__((address_space(1))) void*)g,
                                     (__attribute__((address_space(3))) void*)l, 16, 0, 0);
}
__device__ __forceinline__ int OFFV(const int* __restrict__ offv, const int* __restrict__ part, int v){
    return offv[v] + part[v>>10];
}

// ---------- mega kernel (512 thr): [gemm_p1 128x256 counted-vmcnt 2-buf | gemm64 C1 | csr_fill] ----------
__global__ __launch_bounds__(512) void mega1(const float* __restrict__ Af,          // x_p
                                             const unsigned short* __restrict__ BtP,
                                             unsigned short* __restrict__ P1,
                                             const float* __restrict__ Ac,          // x_c
                                             const float* __restrict__ WcatC,
                                             unsigned short* __restrict__ C1,       // bf16 out
                                             const int* __restrict__ src, const int* __restrict__ dst,
                                             const int* __restrict__ offv, const int* __restrict__ part,
                                             int* __restrict__ cur, int* __restrict__ adj, int E){
    __shared__ __align__(16) unsigned char smem[48*1024];   // 48 KB -> 3 blocks/CU
    const int blk = blockIdx.x;
    const int tid = threadIdx.x;

    if(blk < P1B){
        // ---- gemm_p1: 128x256 tile; A reg-staged f32->bf16 (2x8KB), B gload_lds (2x16KB) ----
        unsigned char* As = smem;               // 2 x 8 KB  (128x32 bf16, swizzled)
        unsigned char* Bs = smem + 16*1024;     // 2 x 16 KB (256x32 bf16, swizzled)
        const int lane = tid & 63;
        const int w    = tid >> 6;              // 0..7
        const int wm   = w >> 2, wn = w & 3;
        const int row0 = blk * 128;
        const int kg = lane >> 4, fr = lane & 15;

        // A staging: thread -> row ar_=tid>>2 (0..127), 16B chunk acc_=tid&3 within 64B row
        const int ar_  = tid >> 2;
        const int acc_ = tid & 3;
        const int asrow = min(row0 + ar_, NPROT-1);
        const float* aG = Af + (size_t)asrow*DIMP + acc_*8;
        const int awoff = ar_*64 + ((acc_ ^ ((ar_>>1)&3)) << 4);   // swizzled ds_write addr

        f32x4 acc[4][4] = {};
        f4 va, vb;

        auto STAGEB = [&](int buf, int k0){
            #pragma unroll
            for(int i=0;i<2;i++){
                int c  = i*512 + tid;
                int r  = c >> 2, cc = c & 3;
                int scc = cc ^ ((r>>1) & 3);
                gload_lds16((const void*)(BtP + (size_t)r*DIMP + k0 + scc*8),
                            (void*)(Bs + buf*16384 + (i*512 + tid)*16));
            }
        };
        auto WRITEA = [&](int buf){
            union { short8 s; unsigned short u[8]; } uu;
            uu.u[0]=f2bf(va.x); uu.u[1]=f2bf(va.y); uu.u[2]=f2bf(va.z); uu.u[3]=f2bf(va.w);
            uu.u[4]=f2bf(vb.x); uu.u[5]=f2bf(vb.y); uu.u[6]=f2bf(vb.z); uu.u[7]=f2bf(vb.w);
            *(short8*)(As + buf*8192 + awoff) = uu.s;
        };

        // ---- prologue: B(0) staged, A(0) -> LDS, A(1) in regs/flight ----
        STAGEB(0, 0);                    // 4 gload_lds
        va = *(const f4*)(aG + 0);       // A(0)
        vb = *(const f4*)(aG + 4);
        WRITEA(0);                       // waits A(0) (and thus B(0)) via compiler vmcnt
        va = *(const f4*)(aG + 32);      // A(1) in flight
        vb = *(const f4*)(aG + 36);
        asm volatile("s_waitcnt lgkmcnt(0)" ::: "memory");
        __builtin_amdgcn_sched_barrier(0);

        for(int t=0; t<KSTEPS; ++t){
            __builtin_amdgcn_s_barrier();
            __builtin_amdgcn_sched_barrier(0);

            if(t+1 < KSTEPS){
                WRITEA((t+1)&1);                 // ds_write A(t+1) (regs loaded a full step ago)
                STAGEB((t+1)&1, (t+1)*32);       // 4 gload_lds -> B(t+1), in flight through step
            }
            __builtin_amdgcn_sched_barrier(0);   // pin: B issued before A reg-loads (FIFO for vmcnt)
            if(t+2 < KSTEPS){
                va = *(const f4*)(aG + (t+2)*32);    // A(t+2): 2 vmem, stay in flight across barrier
                vb = *(const f4*)(aG + (t+2)*32 + 4);
            }

            const unsigned char* Ab = As + (t&1)*8192;
            const unsigned char* Bb = Bs + (t&1)*16384;
            short8 aF[4], bF[4];
            #pragma unroll
            for(int m=0;m<4;m++){
                int r = wm*64 + m*16 + fr;
                aF[m] = *(const short8*)(Ab + r*64 + ((kg ^ ((r>>1)&3))<<4));
            }
            #pragma unroll
            for(int n=0;n<4;n++){
                int r = wn*64 + n*16 + fr;
                bF[n] = *(const short8*)(Bb + r*64 + ((kg ^ ((r>>1)&3))<<4));
            }
            #pragma unroll
            for(int m=0;m<4;m++)
            #pragma unroll
            for(int n=0;n<4;n++)
                acc[m][n] = __builtin_amdgcn_mfma_f32_16x16x32_bf16(aF[m], bF[n], acc[m][n], 0, 0, 0);

            // drain this step's B loads (4 newest-but-A) before next barrier; keep A(t+2) flying
            if(t+2 < KSTEPS)      asm volatile("s_waitcnt vmcnt(2) lgkmcnt(0)" ::: "memory");
            else                  asm volatile("s_waitcnt vmcnt(0) lgkmcnt(0)" ::: "memory");
            __builtin_amdgcn_sched_barrier(0);
        }

        #pragma unroll
        for(int m=0;m<4;m++)
        #pragma unroll
        for(int r=0;r<4;r++){
            int row = row0 + wm*64 + m*16 + kg*4 + r;
            if(row < NPROT){
                #pragma unroll
                for(int n=0;n<4;n++)
                    P1[(size_t)row*256 + wn*64 + n*16 + fr] = f2bf(acc[m][n][r]);
            }
        }
    } else if(blk < P1B + C1B){
        // ---- gemm64: C1[64,64] tile = x_c @ WcatC (f32 math, bf16 store); tid<256 active ----
        float (*As64)[68] = (float(*)[68])smem;
        float (*Bs64)[64] = (float(*)[64])(smem + 16*68*4);
        const int bi = blk - P1B;
        const int row0 = (bi >> 2) * 64;
        const int col0 = (bi & 3) * 64;
        const bool act = tid < 256;
        const int ty = tid >> 4;
        const int tx = tid & 15;
        const int m  = tid >> 2;
        const int kq = (tid & 3) << 2;
        const int kb = tid >> 4;
        const int c4 = (tid & 15) << 2;

        float acc[4][4];
        #pragma unroll
        for(int i=0;i<4;i++)
        #pragma unroll
            for(int j=0;j<4;j++) acc[i][j]=0.f;

        const bool arow_ok = act && (row0 + m) < NCLS;
        const float* Abase = Ac + (size_t)(row0 + min(m,255)) * DIMC + kq;
        const float* Bbase = WcatC + col0 + c4 + (size_t)min(kb,15) * 256;

        for(int k0 = 0; k0 < DIMC; k0 += 16){
            if(act){
                f4 av;
                if(arow_ok) av = *(const f4*)(Abase + k0);
                else        av = make_float4(0.f,0.f,0.f,0.f);
                As64[kq+0][m]=av.x; As64[kq+1][m]=av.y; As64[kq+2][m]=av.z; As64[kq+3][m]=av.w;
                *(f4*)&Bs64[kb][c4] = *(const f4*)(Bbase + (size_t)k0 * 256);
            }
            __syncthreads();
            if(act){
                #pragma unroll
                for(int kk=0;kk<16;kk++){
                    f4 a = *(const f4*)&As64[kk][ty<<2];
                    f4 b = *(const f4*)&Bs64[kk][tx<<2];
                    float ar[4]={a.x,a.y,a.z,a.w};
                    float br[4]={b.x,b.y,b.z,b.w};
                    #pragma unroll
                    for(int i=0;i<4;i++)
                    #pragma unroll
                        for(int j=0;j<4;j++) acc[i][j] += ar[i]*br[j];
                }
            }
            __syncthreads();
        }
        if(act){
            #pragma unroll
            for(int i=0;i<4;i++){
                int r = row0 + (ty<<2) + i;
                if(r < NCLS){
                    ushort4 v;
                    v.x=f2bf(acc[i][0]); v.y=f2bf(acc[i][1]);
                    v.z=f2bf(acc[i][2]); v.w=f2bf(acc[i][3]);
                    *(ushort4*)&C1[(size_t)r*256 + col0 + (tx<<2)] = v;
                }
            }
        }
    } else {
        // ---- csr_fill (512 thr/block) ----
        int e = (blk - P1B - C1B)*512 + tid;
        if(e < E){
            int s = src[e], d = dst[e];
            int pc = atomicAdd(&cur[d],1);        adj[OFFV(offv,part,d)+pc] = s;
            int pp = atomicAdd(&cur[NCLS+s],1);   adj[OFFV(offv,part,NCLS+s)+pp] = d;
        }
    }
}

// ---------- hs GEMM (both node types) + fused att (x==0 blocks) ----------
#define NPB ((NPROT+127)/128)
#define NCB ((NCLS+127)/128)
__global__ __launch_bounds__(256) void gemm_hs(const unsigned short* __restrict__ Ap,
                                               const unsigned short* __restrict__ Ac,
                                               const unsigned short* __restrict__ Btp,
                                               const unsigned short* __restrict__ Btc,
                                               const float* __restrict__ projP,
                                               const float* __restrict__ projC,
                                               unsigned short* __restrict__ Cp,
                                               unsigned short* __restrict__ Cc,
                                               float* __restrict__ attP,
                                               float* __restrict__ attC){
    const bool cls = (int)blockIdx.y >= NPB;
    const unsigned short* A  = cls ? Ac : Ap;
    const unsigned short* Bt = cls ? Btc : Btp;
    unsigned short* C = cls ? Cc : Cp;
    const int M = cls ? NCLS : NPROT;
    const int row0 = (cls ? blockIdx.y - NPB : blockIdx.y) * 128;
    const int col0 = blockIdx.x * 128;

    __shared__ __align__(16) unsigned char As[128*32*2];
    __shared__ __align__(16) unsigned char Bs[128*32*2];
    __shared__ float projS[1024];
    const int tid  = threadIdx.x;
    const int lane = tid & 63;
    const int w    = tid >> 6;
    const int wm   = w >> 1, wn = w & 1;
    const int kg = lane >> 4, fr = lane & 15;

    f32x4 acc[4][4] = {};

    for(int k0 = 0; k0 < 128; k0 += 32){
        #pragma unroll
        for(int i=0;i<2;i++){
            int c  = i*256 + w*64 + lane;
            int r  = c >> 2, cc = c & 3;
            int scc = cc ^ ((r>>1) & 3);
            int srow = min(row0 + r, M-1);
            gload_lds16((const void*)(A + (size_t)srow*128 + k0 + scc*8),
                        (void*)(As + (i*256 + w*64)*16));
        }
        #pragma unroll
        for(int i=0;i<2;i++){
            int c  = i*256 + w*64 + lane;
            int r  = c >> 2, cc = c & 3;
            int scc = cc ^ ((r>>1) & 3);
            gload_lds16((const void*)(Bt + (size_t)(col0 + r)*128 + k0 + scc*8),
                        (void*)(Bs + (i*256 + w*64)*16));
        }
        __syncthreads();

        short8 aF[4], bF[4];
        #pragma unroll
        for(int m=0;m<4;m++){
            int r = wm*64 + m*16 + fr;
            int b0 = (r*64 + kg*16) ^ (((r>>1)&3)<<4);
            aF[m] = *(const short8*)(As + b0);
        }
        #pragma unroll
        for(int n=0;n<4;n++){
            int r = wn*64 + n*16 + fr;
            int b0 = (r*64 + kg*16) ^ (((r>>1)&3)<<4);
            bF[n] = *(const short8*)(Bs + b0);
        }
        #pragma unroll
        for(int m=0;m<4;m++)
        #pragma unroll
        for(int n=0;n<4;n++)
            acc[m][n] = __builtin_amdgcn_mfma_f32_16x16x32_bf16(aF[m], bF[n], acc[m][n], 0, 0, 0);
        __syncthreads();
    }

    #pragma unroll
    for(int m=0;m<4;m++)
    #pragma unroll
    for(int r=0;r<4;r++){
        int row = row0 + wm*64 + m*16 + kg*4 + r;
        if(row < M){
            #pragma unroll
            for(int n=0;n<4;n++)
                C[(size_t)row*512 + col0 + wn*64 + n*16 + fr] = f2bf(acc[m][n][r]);
        }
    }

    // fused att: only x==0 blocks; att[row,0:8] = h[row,:] @ proj[128,8]
    if(blockIdx.x == 0){
        const float* proj = cls ? projC : projP;
        float* att = cls ? attC : attP;
        for(int i=tid;i<1024;i+=256) projS[i] = proj[i];
        __syncthreads();
        int ri = tid >> 1, cb = (tid & 1)*4;
        int row = row0 + ri;
        if(row < M){
            const unsigned short* ar = A + (size_t)row*128;
            float s0=0.f,s1=0.f,s2=0.f,s3=0.f;
            #pragma unroll
            for(int kk=0;kk<16;kk++){
                short8 a8 = *(const short8*)(ar + kk*8);
                #pragma unroll
                for(int q=0;q<8;q++){
                    float av = bf2f((unsigned short)a8[q]);
                    const float* pr = &projS[(kk*8+q)*8 + cb];
                    s0 += av*pr[0]; s1 += av*pr[1]; s2 += av*pr[2]; s3 += av*pr[3];
                }
            }
            f4 o = make_float4(s0,s1,s2,s3);
            *(f4*)&att[(size_t)row*8 + cb] = o;
        }
    }
}

// ---------- merged setup: prep_weights ∪ folds ∪ deg ----------
__global__ void setup(const float* __restrict__ Wl_pc, const float* __restrict__ Wr_cp,
                      const float* __restrict__ Wl_cp, const float* __restrict__ Wr_pc,
                      const float* __restrict__ pcWs, const float* __restrict__ pcAs,
                      const float* __restrict__ pcWd, const float* __restrict__ pcAd,
                      const float* __restrict__ cpWs, const float* __restrict__ cpAs,
                      const float* __restrict__ cpWd, const float* __restrict__ cpAd,
                      const float* __restrict__ lpW, const float* __restrict__ lpb,
                      const float* __restrict__ lcW, const float* __restrict__ lcb,
                      const float* __restrict__ linkW,
                      const int* __restrict__ src, const int* __restrict__ dst,
                      unsigned short* __restrict__ BtP, float* __restrict__ WcatC,
                      unsigned short* __restrict__ BtSp, unsigned short* __restrict__ BtSc,
                      float* __restrict__ projP, float* __restrict__ projC,
                      float* __restrict__ w_p, float* __restrict__ w_c,
                      float* __restrict__ cpc,
                      int* __restrict__ deg, int E){
    int blk = blockIdx.x, tid = threadIdx.x;
    if(blk < 2048){
        int t = blk*256 + tid;
        if(t < 327680){
            int n = t / 1280, k = t % 1280;
            float v = (n<128) ? Wl_pc[(size_t)k*128+n] : Wr_cp[(size_t)k*128+n-128];
            BtP[t] = f2bf(v);
        } else if(t < 393216){
            int i = t - 327680; int k = i>>8, j = i&255;
            WcatC[i] = (j<128) ? Wl_cp[(size_t)k*128+j] : Wr_pc[(size_t)k*128+j-128];
        } else if(t < 458752){
            int i = t - 393216; int n = i>>7, k = i&127;
            BtSp[i] = f2bf(pcWs[(size_t)k*512+n]);
        } else {
            int i = t - 458752; int n = i>>7, k = i&127;
            BtSc[i] = f2bf(cpWs[(size_t)k*512+n]);
        }
    } else if(blk < 2056){
        int sec = (blk-2048) >> 1;
        int t = ((blk-2048) & 1)*256 + tid;
        const float *W, *a; float* proj; int colbase;
        if(sec==0){ W=pcWs; a=pcAs; proj=projP; colbase=0; }
        else if(sec==1){ W=cpWd; a=cpAd; proj=projP; colbase=4; }
        else if(sec==2){ W=pcWd; a=pcAd; proj=projC; colbase=0; }
        else { W=cpWs; a=cpAs; proj=projC; colbase=4; }
        int k = t >> 2, h = t & 3;
        const float* w = W + (size_t)k*512 + h*128;
        const float* av = a + h*128;
        float s=0.f;
        for(int c=0;c<128;c++) s += w[c]*av[c];
        proj[k*8 + colbase + h] = s;
    } else if(blk == 2056){
        if(tid < 128){
            float s=0.f;
            for(int o=0;o<128;o++) s += lpW[(size_t)tid*128+o]*linkW[o];
            w_p[tid]=s;
        } else {
            int j=tid-128;
            float s=0.f;
            for(int o=0;o<128;o++) s += lcW[(size_t)j*128+o]*linkW[128+o];
            w_c[j]=s;
        }
        if(tid==0){ float s=0.f; for(int o=0;o<128;o++) s+=lpb[o]*linkW[o];      cpc[0]=s; }
        if(tid==1){ float s=0.f; for(int o=0;o<128;o++) s+=lcb[o]*linkW[128+o];  cpc[1]=s; }
    } else {
        int e = (blk-2057)*256 + tid;
        if(e < E){
            atomicAdd(&deg[dst[e]],1);
            atomicAdd(&deg[NCLS + src[e]],1);
        }
    }
}

// ---------- hierarchical exclusive scan ----------
__global__ __launch_bounds__(1024) void scan1(const int* __restrict__ in, int* __restrict__ out,
                                              int* __restrict__ part, int n){
    __shared__ int buf[1024];
    int tid = threadIdx.x;
    int g = blockIdx.x*1024 + tid;
    int v = (g<n) ? in[g] : 0;
    buf[tid] = v;
    __syncthreads();
    for(int o=1;o<1024;o<<=1){
        int t = (tid>=o) ? buf[tid-o] : 0;
        __syncthreads();
        buf[tid] += t;
        __syncthreads();
    }
    if(g<n) out[g] = buf[tid] - v;
    if(tid==1023) part[blockIdx.x] = buf[1023];
}
__global__ __launch_bounds__(64) void scan2(int* __restrict__ part, int nb,
                                            int* __restrict__ offv, int n){
    int tid = threadIdx.x;
    int orig = (tid<nb) ? part[tid] : 0;
    int v = orig;
    #pragma unroll
    for(int o=1;o<64;o<<=1){
        int t = __shfl_up(v, o);
        if(tid>=o) v += t;
    }
    int total = __shfl(v, nb-1);
    if(tid<nb) part[tid] = v - orig;
    if(tid == (n>>10)) offv[n] = total - (v - orig);
}

// ---------- merged SAGE (both types; C1 bf16) ----------
__global__ __launch_bounds__(256) void sage_all(const int* __restrict__ offv, const int* __restrict__ part,
                                                const int* __restrict__ adj,
                                                const unsigned short* __restrict__ P1,
                                                const unsigned short* __restrict__ C1,
                                                const float* __restrict__ bl_pc, const float* __restrict__ bl_cp,
                                                unsigned short* __restrict__ h_c, unsigned short* __restrict__ h_p){
    int v = blockIdx.x*4 + (threadIdx.x>>6);
    int l = threadIdx.x & 63;
    if(v >= SCAN_N) return;
    int b = OFFV(offv,part,v), deg = OFFV(offv,part,v+1)-b;
    float a0=0.f, a1=0.f;
    float inv = 1.f/(float)max(deg,1);
    if(v < NCLS){
        #pragma unroll 4
        for(int i=0;i<deg;i++){
            int s = adj[b+i];
            ushort2 w = *((const ushort2*)P1 + (size_t)s*128 + l);
            a0 += bf2f(w.x); a1 += bf2f(w.y);
        }
        ushort2 sv = *((const ushort2*)C1 + (size_t)v*128 + 64 + l);
        float h0 = fmaxf(a0*inv + bl_pc[2*l]   + bf2f(sv.x), 0.f);
        float h1 = fmaxf(a1*inv + bl_pc[2*l+1] + bf2f(sv.y), 0.f);
        ushort2 o; o.x=f2bf(h0); o.y=f2bf(h1);
        *((ushort2*)h_c + (size_t)v*64 + l) = o;
    } else {
        int m = v - NCLS;
        #pragma unroll 4
        for(int i=0;i<deg;i++){
            int d = adj[b+i];
            ushort2 w = *((const ushort2*)C1 + (size_t)d*128 + l);
            a0 += bf2f(w.x); a1 += bf2f(w.y);
        }
        ushort2 sv = *((const ushort2*)P1 + (size_t)m*128 + 64 + l);
        float h0 = fmaxf(a0*inv + bl_cp[2*l]   + bf2f(sv.x), 0.f);
        float h1 = fmaxf(a1*inv + bl_cp[2*l+1] + bf2f(sv.y), 0.f);
        ushort2 o; o.x=f2bf(h0); o.y=f2bf(h1);
        *((ushort2*)h_p + (size_t)m*64 + l) = o;
    }
}

// ---------- fused GAT: thread j = head (j>>5) x 4 channels (4*(j&31)) ----------
__global__ __launch_bounds__(128) void gat_all(const int* __restrict__ offv, const int* __restrict__ part,
                                               const int* __restrict__ adj,
                                               const float* __restrict__ attP, const float* __restrict__ attC,
                                               const unsigned short* __restrict__ hs_p,
                                               const unsigned short* __restrict__ hs_c,
                                               const float* __restrict__ gb_pc, const float* __restrict__ gb_cp,
                                               const float* __restrict__ w_c, const float* __restrict__ w_p,
                                               const float* __restrict__ cpc,
                                               float* __restrict__ u_c, float* __restrict__ u_p){
    __shared__ float ald[4];
    __shared__ int   adjS[32];
    __shared__ float eeS[32*4];
    __shared__ float den8[8];
    __shared__ f4    red4[32];

    int n = blockIdx.x;
    const bool cls = n < NCLS;
    const int node = cls ? n : n - NCLS;
    const float* attS = cls ? attP : attC;
    const float* attD = cls ? attC : attP;
    const int abase = cls ? 0 : 4;
    const unsigned short* hs = cls ? hs_p : hs_c;
    const float* gb = cls ? gb_pc : gb_cp;
    const float* wv = cls ? w_c : w_p;
    float* u = cls ? u_c : u_p;
    const int cidx = cls ? 1 : 0;

    int j = threadIdx.x;
    const int hh = j >> 5;          // head
    const int q  = j & 31;          // channel group: channels 4q..4q+3
    int b = OFFV(offv,part,n), deg = OFFV(offv,part,n+1)-b;
    if(j < 4) ald[j] = attD[(size_t)node*8 + abase + j];

    float a0=0.f, a1=0.f, a2=0.f, a3=0.f;
    float denP = 0.f;

    for(int base=0; base<deg; base+=32){
        int cnt = min(32, deg-base);
        if(j < cnt) adjS[j] = adj[b+base+j];
        __syncthreads();
        if(j < cnt*4){
            int i = j>>2, h = j&3;
            int s = adjS[i];
            float e = attS[(size_t)s*8 + abase + h] + ald[h];
            e = e > 0.f ? e : 0.2f*e;
            float ee = __expf(e);
            eeS[j] = ee;
            denP += ee;
        }
        __syncthreads();
        #pragma unroll 4
        for(int ii=0; ii<cnt; ii++){
            int s = adjS[ii];
            float ee = eeS[ii*4 + hh];
            ushort4 v = *(const ushort4*)(hs + (size_t)s*512 + hh*128 + q*4);
            a0 += ee*bf2f(v.x); a1 += ee*bf2f(v.y);
            a2 += ee*bf2f(v.z); a3 += ee*bf2f(v.w);
        }
        __syncthreads();
    }

    // per-head denominators: thread j contributed to head (j&3); shfl-reduce per wave
    float dp = denP;
    dp += __shfl_xor(dp, 4);
    dp += __shfl_xor(dp, 8);
    dp += __shfl_xor(dp, 16);
    dp += __shfl_xor(dp, 32);
    if((j & 63) < 4) den8[(j>>6)*4 + (j&3)] = dp;
    __syncthreads();

    float den_h = den8[hh] + den8[4+hh];
    float inv = (deg > 0) ? 0.25f/den_h : 0.f;
    a0 *= inv; a1 *= inv; a2 *= inv; a3 *= inv;

    // head-mean: pair-reduce within wave (head0+1 / head2+3), then cross-wave via LDS
    a0 += __shfl_xor(a0, 32); a1 += __shfl_xor(a1, 32);
    a2 += __shfl_xor(a2, 32); a3 += __shfl_xor(a3, 32);
    if(j >= 64 && j < 96) red4[q] = make_float4(a0,a1,a2,a3);
    __syncthreads();
    float val = 0.f;
    if(j < 32){
        f4 r = red4[q];
        float t0 = a0 + r.x, t1 = a1 + r.y, t2 = a2 + r.z, t3 = a3 + r.w;
        const float* gbq = gb + q*4;
        const float* wvq = wv + q*4;
        val = fmaxf(t0 + gbq[0], 0.f)*wvq[0]
            + fmaxf(t1 + gbq[1], 0.f)*wvq[1]
            + fmaxf(t2 + gbq[2], 0.f)*wvq[2]
            + fmaxf(t3 + gbq[3], 0.f)*wvq[3];
    }
    #pragma unroll
    for(int o=16;o;o>>=1) val += __shfl_down(val, o);
    if(j == 0) u[node] = val + cpc[cidx];
}

__global__ void link_out(const int* __restrict__ els, const int* __restrict__ eld,
                         const float* __restrict__ u_p, const float* __restrict__ u_c,
                         const float* __restrict__ linkb, float* __restrict__ out, int EL){
    int i = blockIdx.x*256 + threadIdx.x;
    if(i >= EL) return;
    float x = u_p[els[i]] + u_c[eld[i]] + linkb[0];
    out[i] = 1.f/(1.f + __expf(-x));
}

// ---------- host ----------
extern "C" void kernel_launch(void* const* d_in, const int* in_sizes, int n_in,
                              void* d_out, int out_size, void* d_ws, size_t ws_size,
                              hipStream_t stream){
    const float* x_p  = (const float*)d_in[0];
    const float* x_c  = (const float*)d_in[1];
    const int*   src  = (const int*)d_in[2];
    const int*   dst  = (const int*)d_in[3];
    const int*   els  = (const int*)d_in[4];
    const int*   eld  = (const int*)d_in[5];
    const float* sage_pc_Wl = (const float*)d_in[6];
    const float* sage_pc_bl = (const float*)d_in[7];
    const float* sage_pc_Wr = (const float*)d_in[8];
    const float* sage_cp_Wl = (const float*)d_in[9];
    const float* sage_cp_bl = (const float*)d_in[10];
    const float* sage_cp_Wr = (const float*)d_in[11];
    const float* gat_pc_Wsrc = (const float*)d_in[12];
    const float* gat_pc_Wdst = (const float*)d_in[13];
    const float* gat_pc_asrc = (const float*)d_in[14];
    const float* gat_pc_adst = (const float*)d_in[15];
    const float* gat_pc_b    = (const float*)d_in[16];
    const float* gat_cp_Wsrc = (const float*)d_in[17];
    const float* gat_cp_Wdst = (const float*)d_in[18];
    const float* gat_cp_asrc = (const float*)d_in[19];
    const float* gat_cp_adst = (const float*)d_in[20];
    const float* gat_cp_b    = (const float*)d_in[21];
    const float* lin_p_W = (const float*)d_in[22];
    const float* lin_p_b = (const float*)d_in[23];
    const float* lin_c_W = (const float*)d_in[24];
    const float* lin_c_b = (const float*)d_in[25];
    const float* link_W  = (const float*)d_in[26];
    const float* link_b  = (const float*)d_in[27];

    const int E  = in_sizes[2];
    const int EL = in_sizes[4];

    float* ws = (float*)d_ws;
    size_t off = 0;
    auto alloc = [&](size_t n)->float*{ float* p = ws + off; off += (n + 3) & ~(size_t)3; return p; };

    unsigned short* BtP  = (unsigned short*)alloc((size_t)256*DIMP/2);
    float* WcatC = alloc((size_t)DIMC*256);
    unsigned short* BtSp = (unsigned short*)alloc((size_t)512*128/2);
    unsigned short* BtSc = (unsigned short*)alloc((size_t)512*128/2);
    unsigned short* P1   = (unsigned short*)alloc((size_t)NPROT*256/2);
    unsigned short* C1   = (unsigned short*)alloc((size_t)NCLS*256/2);
    unsigned short* h_p  = (unsigned short*)alloc((size_t)NPROT*128/2);
    unsigned short* h_c  = (unsigned short*)alloc((size_t)NCLS*128/2);
    unsigned short* hs_p = (unsigned short*)alloc((size_t)NPROT*512/2);
    unsigned short* hs_c = (unsigned short*)alloc((size_t)NCLS*512/2);
    float* attP  = alloc((size_t)NPROT*8);
    float* attC  = alloc((size_t)NCLS*8);
    float* projP = alloc(128*8);
    float* projC = alloc(128*8);
    float* w_p   = alloc(128);
    float* w_c   = alloc(128);
    float* cpc   = alloc(4);
    int* degcur = (int*)alloc((size_t)2*SCAN_N);   // deg | cur (one memset)
    int* deg = degcur;
    int* cur = degcur + SCAN_N;
    int* offv = (int*)alloc(SCAN_N+1);
    int* part = (int*)alloc(64);
    int* adj  = (int*)alloc((size_t)2*E);
    float* u_p = alloc(NPROT);
    float* u_c = alloc(NCLS);
    if(off*4 > ws_size) return;

    hipMemsetAsync(degcur, 0, (size_t)2*SCAN_N*4, stream);

    // --- setup: weight prep + folds + degree count ---
    setup<<<2057 + (E+255)/256, 256, 0, stream>>>(
        sage_pc_Wl, sage_cp_Wr, sage_cp_Wl, sage_pc_Wr,
        gat_pc_Wsrc, gat_pc_asrc, gat_pc_Wdst, gat_pc_adst,
        gat_cp_Wsrc, gat_cp_asrc, gat_cp_Wdst, gat_cp_adst,
        lin_p_W, lin_p_b, lin_c_W, lin_c_b, link_W,
        src, dst,
        BtP, WcatC, BtSp, BtSc, projP, projC, w_p, w_c, cpc, deg, E);

    // --- scan ---
    const int NB = (SCAN_N + 1023)/1024;
    scan1<<<NB,1024,0,stream>>>(deg, offv, part, SCAN_N);
    scan2<<<1,64,0,stream>>>(part, NB, offv, SCAN_N);

    // --- mega: gemm_p1(counted-vmcnt 2-buf) | gemm64(C1 bf16) | csr_fill ---
    const int FILLB = (E+511)/512;
    mega1<<<P1B + C1B + FILLB, 512, 0, stream>>>(x_p, BtP, P1, x_c, WcatC, C1,
                                                 src, dst, offv, part, cur, adj, E);

    // --- SAGE ---
    sage_all<<<(SCAN_N+3)/4,256,0,stream>>>(offv, part, adj, P1, C1, sage_pc_bl, sage_cp_bl, h_c, h_p);

    // --- layer 2 GEMM (+ fused att) ---
    gemm_hs<<<dim3(4,NPB+NCB),256,0,stream>>>(h_p, h_c, BtSp, BtSc, projP, projC,
                                              hs_p, hs_c, attP, attC);

    // --- fused GAT + output head ---
    gat_all<<<SCAN_N,128,0,stream>>>(offv, part, adj, attP, attC, hs_p, hs_c,
                                     gat_pc_b, gat_cp_b, w_c, w_p, cpc, u_c, u_p);

    link_out<<<(EL+255)/256,256,0,stream>>>(els, eld, u_p, u_c, link_b, (float*)d_out, EL);
}

// Round 14
// 287.815 us; speedup vs baseline: 1.1258x; 1.0969x over previous
//
#include <hip/hip_runtime.h>
#include <math.h>

#define NPROT 50000
#define NCLS  5000
#define DIMP  1280
#define DIMC  256
#define SCAN_N (NCLS + NPROT)
#define KSTEPS (DIMP/32)          // 40

#define P1B  ((NPROT+127)/128)    // 391 gemm_p1 blocks (128x256 tile)
#define C1BY ((NCLS+63)/64)       // 79
#define C1B  (4*C1BY)             // 316 gemm64 blocks

typedef float4 f4;
typedef __attribute__((ext_vector_type(8))) short short8;
typedef __attribute__((ext_vector_type(4))) float f32x4;

// ---------- helpers ----------
__device__ __forceinline__ unsigned short f2bf(float f){   // RNE
    unsigned u = __float_as_uint(f);
    u += 0x7FFFu + ((u >> 16) & 1u);
    return (unsigned short)(u >> 16);
}
__device__ __forceinline__ float bf2f(unsigned short b){
    return __uint_as_float(((unsigned)b) << 16);
}
__device__ __forceinline__ void gload_lds16(const void* g, void* l){
    __builtin_amdgcn_global_load_lds((const __attribute__((address_space(1))) void*)g,
                                     (__attribute__((address_space(3))) void*)l, 16, 0, 0);
}
__device__ __forceinline__ int OFFV(const int* __restrict__ offv, const int* __restrict__ part, int v){
    return offv[v] + part[v>>10];
}

// ---------- mega kernel (512 thr): [gemm64 C1 | csr_fill | gemm_p1 r8-dbuf] ----------
// short branches FIRST in grid so CUs fill with P1 blocks during the long phase.
__global__ __launch_bounds__(512) void mega1(const float* __restrict__ Af,          // x_p
                                             const unsigned short* __restrict__ BtP,
                                             unsigned short* __restrict__ P1,
                                             const float* __restrict__ Ac,          // x_c
                                             const float* __restrict__ WcatC,
                                             unsigned short* __restrict__ C1,       // bf16 out
                                             const int* __restrict__ src, const int* __restrict__ dst,
                                             const int* __restrict__ offv, const int* __restrict__ part,
                                             int* __restrict__ cur, int* __restrict__ adj, int E){
    __shared__ __align__(16) unsigned char smem[48*1024];   // 48 KB -> 3 blocks/CU
    const int blk = blockIdx.x;
    const int tid = threadIdx.x;
    const int FILLB = (E + 511) / 512;

    if(blk < C1B){
        // ---- gemm64: C1[64,64] tile = x_c @ WcatC (f32 math, bf16 store); tid<256 active ----
        float (*As64)[68] = (float(*)[68])smem;
        float (*Bs64)[64] = (float(*)[64])(smem + 16*68*4);
        const int bi = blk;
        const int row0 = (bi >> 2) * 64;
        const int col0 = (bi & 3) * 64;
        const bool act = tid < 256;
        const int ty = tid >> 4;
        const int tx = tid & 15;
        const int m  = tid >> 2;
        const int kq = (tid & 3) << 2;
        const int kb = tid >> 4;
        const int c4 = (tid & 15) << 2;

        float acc[4][4];
        #pragma unroll
        for(int i=0;i<4;i++)
        #pragma unroll
            for(int j=0;j<4;j++) acc[i][j]=0.f;

        const bool arow_ok = act && (row0 + m) < NCLS;
        const float* Abase = Ac + (size_t)(row0 + min(m,255)) * DIMC + kq;
        const float* Bbase = WcatC + col0 + c4 + (size_t)min(kb,15) * 256;

        for(int k0 = 0; k0 < DIMC; k0 += 16){
            if(act){
                f4 av;
                if(arow_ok) av = *(const f4*)(Abase + k0);
                else        av = make_float4(0.f,0.f,0.f,0.f);
                As64[kq+0][m]=av.x; As64[kq+1][m]=av.y; As64[kq+2][m]=av.z; As64[kq+3][m]=av.w;
                *(f4*)&Bs64[kb][c4] = *(const f4*)(Bbase + (size_t)k0 * 256);
            }
            __syncthreads();
            if(act){
                #pragma unroll
                for(int kk=0;kk<16;kk++){
                    f4 a = *(const f4*)&As64[kk][ty<<2];
                    f4 b = *(const f4*)&Bs64[kk][tx<<2];
                    float ar[4]={a.x,a.y,a.z,a.w};
                    float br[4]={b.x,b.y,b.z,b.w};
                    #pragma unroll
                    for(int i=0;i<4;i++)
                    #pragma unroll
                        for(int j=0;j<4;j++) acc[i][j] += ar[i]*br[j];
                }
            }
            __syncthreads();
        }
        if(act){
            #pragma unroll
            for(int i=0;i<4;i++){
                int r = row0 + (ty<<2) + i;
                if(r < NCLS){
                    ushort4 v;
                    v.x=f2bf(acc[i][0]); v.y=f2bf(acc[i][1]);
                    v.z=f2bf(acc[i][2]); v.w=f2bf(acc[i][3]);
                    *(ushort4*)&C1[(size_t)r*256 + col0 + (tx<<2)] = v;
                }
            }
        }
    } else if(blk < C1B + FILLB){
        // ---- csr_fill (512 thr/block) ----
        int e = (blk - C1B)*512 + tid;
        if(e < E){
            int s = src[e], d = dst[e];
            int pc = atomicAdd(&cur[d],1);        adj[OFFV(offv,part,d)+pc] = s;
            int pp = atomicAdd(&cur[NCLS+s],1);   adj[OFFV(offv,part,NCLS+s)+pp] = d;
        }
    } else {
        // ---- gemm_p1: 128x256 tile; A reg-staged f32->bf16 (2x8KB), B gload_lds (2x16KB), dbuf ----
        const int pblk = blk - C1B - FILLB;
        unsigned char* As = smem;               // 2 x 8 KB
        unsigned char* Bs = smem + 16*1024;     // 2 x 16 KB
        const int lane = tid & 63;
        const int w    = tid >> 6;              // 0..7
        const int wm   = w >> 2, wn = w & 3;
        const int row0 = pblk * 128;
        const int kg = lane >> 4, fr = lane & 15;

        const int ar_  = tid >> 2;
        const int acc_ = tid & 3;
        const int asrow = min(row0 + ar_, NPROT-1);
        const float* aG = Af + (size_t)asrow*DIMP + acc_*8;
        const int awoff = ar_*64 + ((acc_ ^ ((ar_>>1)&3)) << 4);

        f32x4 acc[4][4] = {};
        f4 va, vb;

        auto STAGEB = [&](int buf, int k0){
            #pragma unroll
            for(int i=0;i<2;i++){
                int c  = i*512 + tid;
                int r  = c >> 2, cc = c & 3;
                int scc = cc ^ ((r>>1) & 3);
                gload_lds16((const void*)(BtP + (size_t)r*DIMP + k0 + scc*8),
                            (void*)(Bs + buf*16384 + (i*512 + tid)*16));
            }
        };
        auto WRITEA = [&](int buf){
            union { short8 s; unsigned short u[8]; } uu;
            uu.u[0]=f2bf(va.x); uu.u[1]=f2bf(va.y); uu.u[2]=f2bf(va.z); uu.u[3]=f2bf(va.w);
            uu.u[4]=f2bf(vb.x); uu.u[5]=f2bf(vb.y); uu.u[6]=f2bf(vb.z); uu.u[7]=f2bf(vb.w);
            *(short8*)(As + buf*8192 + awoff) = uu.s;
        };

        va = *(const f4*)(aG + 0);
        vb = *(const f4*)(aG + 4);
        STAGEB(0, 0);
        WRITEA(0);
        __syncthreads();

        for(int t=0; t<KSTEPS; ++t){
            const int cb = t & 1;
            if(t+1 < KSTEPS){
                va = *(const f4*)(aG + (t+1)*32);       // in flight during MFMA
                vb = *(const f4*)(aG + (t+1)*32 + 4);
                STAGEB(cb^1, (t+1)*32);
            }

            const unsigned char* Ab = As + cb*8192;
            const unsigned char* Bb = Bs + cb*16384;
            short8 aF[4], bF[4];
            #pragma unroll
            for(int m=0;m<4;m++){
                int r = wm*64 + m*16 + fr;
                aF[m] = *(const short8*)(Ab + r*64 + ((kg ^ ((r>>1)&3))<<4));
            }
            #pragma unroll
            for(int n=0;n<4;n++){
                int r = wn*64 + n*16 + fr;
                bF[n] = *(const short8*)(Bb + r*64 + ((kg ^ ((r>>1)&3))<<4));
            }
            #pragma unroll
            for(int m=0;m<4;m++)
            #pragma unroll
            for(int n=0;n<4;n++)
                acc[m][n] = __builtin_amdgcn_mfma_f32_16x16x32_bf16(aF[m], bF[n], acc[m][n], 0, 0, 0);

            if(t+1 < KSTEPS) WRITEA(cb^1);      // write-late
            __syncthreads();
        }

        #pragma unroll
        for(int m=0;m<4;m++)
        #pragma unroll
        for(int r=0;r<4;r++){
            int row = row0 + wm*64 + m*16 + kg*4 + r;
            if(row < NPROT){
                #pragma unroll
                for(int n=0;n<4;n++)
                    P1[(size_t)row*256 + wn*64 + n*16 + fr] = f2bf(acc[m][n][r]);
            }
        }
    }
}

// ---------- hs GEMM (both node types) + fused att (x==0 blocks) ----------
#define NPB ((NPROT+127)/128)
#define NCB ((NCLS+127)/128)
__global__ __launch_bounds__(256) void gemm_hs(const unsigned short* __restrict__ Ap,
                                               const unsigned short* __restrict__ Ac,
                                               const unsigned short* __restrict__ Btp,
                                               const unsigned short* __restrict__ Btc,
                                               const float* __restrict__ projP,
                                               const float* __restrict__ projC,
                                               unsigned short* __restrict__ Cp,
                                               unsigned short* __restrict__ Cc,
                                               float* __restrict__ attP,
                                               float* __restrict__ attC){
    const bool cls = (int)blockIdx.y >= NPB;
    const unsigned short* A  = cls ? Ac : Ap;
    const unsigned short* Bt = cls ? Btc : Btp;
    unsigned short* C = cls ? Cc : Cp;
    const int M = cls ? NCLS : NPROT;
    const int row0 = (cls ? blockIdx.y - NPB : blockIdx.y) * 128;
    const int col0 = blockIdx.x * 128;

    __shared__ __align__(16) unsigned char As[128*32*2];
    __shared__ __align__(16) unsigned char Bs[128*32*2];
    __shared__ float projS[1024];
    const int tid  = threadIdx.x;
    const int lane = tid & 63;
    const int w    = tid >> 6;
    const int wm   = w >> 1, wn = w & 1;
    const int kg = lane >> 4, fr = lane & 15;

    f32x4 acc[4][4] = {};

    for(int k0 = 0; k0 < 128; k0 += 32){
        #pragma unroll
        for(int i=0;i<2;i++){
            int c  = i*256 + w*64 + lane;
            int r  = c >> 2, cc = c & 3;
            int scc = cc ^ ((r>>1) & 3);
            int srow = min(row0 + r, M-1);
            gload_lds16((const void*)(A + (size_t)srow*128 + k0 + scc*8),
                        (void*)(As + (i*256 + w*64)*16));
        }
        #pragma unroll
        for(int i=0;i<2;i++){
            int c  = i*256 + w*64 + lane;
            int r  = c >> 2, cc = c & 3;
            int scc = cc ^ ((r>>1) & 3);
            gload_lds16((const void*)(Bt + (size_t)(col0 + r)*128 + k0 + scc*8),
                        (void*)(Bs + (i*256 + w*64)*16));
        }
        __syncthreads();

        short8 aF[4], bF[4];
        #pragma unroll
        for(int m=0;m<4;m++){
            int r = wm*64 + m*16 + fr;
            int b0 = (r*64 + kg*16) ^ (((r>>1)&3)<<4);
            aF[m] = *(const short8*)(As + b0);
        }
        #pragma unroll
        for(int n=0;n<4;n++){
            int r = wn*64 + n*16 + fr;
            int b0 = (r*64 + kg*16) ^ (((r>>1)&3)<<4);
            bF[n] = *(const short8*)(Bs + b0);
        }
        #pragma unroll
        for(int m=0;m<4;m++)
        #pragma unroll
        for(int n=0;n<4;n++)
            acc[m][n] = __builtin_amdgcn_mfma_f32_16x16x32_bf16(aF[m], bF[n], acc[m][n], 0, 0, 0);
        __syncthreads();
    }

    #pragma unroll
    for(int m=0;m<4;m++)
    #pragma unroll
    for(int r=0;r<4;r++){
        int row = row0 + wm*64 + m*16 + kg*4 + r;
        if(row < M){
            #pragma unroll
            for(int n=0;n<4;n++)
                C[(size_t)row*512 + col0 + wn*64 + n*16 + fr] = f2bf(acc[m][n][r]);
        }
    }

    // fused att: only x==0 blocks; att[row,0:8] = h[row,:] @ proj[128,8]
    if(blockIdx.x == 0){
        const float* proj = cls ? projC : projP;
        float* att = cls ? attC : attP;
        for(int i=tid;i<1024;i+=256) projS[i] = proj[i];
        __syncthreads();
        int ri = tid >> 1, cb = (tid & 1)*4;
        int row = row0 + ri;
        if(row < M){
            const unsigned short* ar = A + (size_t)row*128;
            float s0=0.f,s1=0.f,s2=0.f,s3=0.f;
            #pragma unroll
            for(int kk=0;kk<16;kk++){
                short8 a8 = *(const short8*)(ar + kk*8);
                #pragma unroll
                for(int q=0;q<8;q++){
                    float av = bf2f((unsigned short)a8[q]);
                    const float* pr = &projS[(kk*8+q)*8 + cb];
                    s0 += av*pr[0]; s1 += av*pr[1]; s2 += av*pr[2]; s3 += av*pr[3];
                }
            }
            f4 o = make_float4(s0,s1,s2,s3);
            *(f4*)&att[(size_t)row*8 + cb] = o;
        }
    }
}

// ---------- merged setup: prep_weights ∪ folds ∪ deg ----------
__global__ void setup(const float* __restrict__ Wl_pc, const float* __restrict__ Wr_cp,
                      const float* __restrict__ Wl_cp, const float* __restrict__ Wr_pc,
                      const float* __restrict__ pcWs, const float* __restrict__ pcAs,
                      const float* __restrict__ pcWd, const float* __restrict__ pcAd,
                      const float* __restrict__ cpWs, const float* __restrict__ cpAs,
                      const float* __restrict__ cpWd, const float* __restrict__ cpAd,
                      const float* __restrict__ lpW, const float* __restrict__ lpb,
                      const float* __restrict__ lcW, const float* __restrict__ lcb,
                      const float* __restrict__ linkW,
                      const int* __restrict__ src, const int* __restrict__ dst,
                      unsigned short* __restrict__ BtP, float* __restrict__ WcatC,
                      unsigned short* __restrict__ BtSp, unsigned short* __restrict__ BtSc,
                      float* __restrict__ projP, float* __restrict__ projC,
                      float* __restrict__ w_p, float* __restrict__ w_c,
                      float* __restrict__ cpc,
                      int* __restrict__ deg, int E){
    int blk = blockIdx.x, tid = threadIdx.x;
    if(blk < 2048){
        int t = blk*256 + tid;
        if(t < 327680){
            int n = t / 1280, k = t % 1280;
            float v = (n<128) ? Wl_pc[(size_t)k*128+n] : Wr_cp[(size_t)k*128+n-128];
            BtP[t] = f2bf(v);
        } else if(t < 393216){
            int i = t - 327680; int k = i>>8, j = i&255;
            WcatC[i] = (j<128) ? Wl_cp[(size_t)k*128+j] : Wr_pc[(size_t)k*128+j-128];
        } else if(t < 458752){
            int i = t - 393216; int n = i>>7, k = i&127;
            BtSp[i] = f2bf(pcWs[(size_t)k*512+n]);
        } else {
            int i = t - 458752; int n = i>>7, k = i&127;
            BtSc[i] = f2bf(cpWs[(size_t)k*512+n]);
        }
    } else if(blk < 2056){
        int sec = (blk-2048) >> 1;
        int t = ((blk-2048) & 1)*256 + tid;
        const float *W, *a; float* proj; int colbase;
        if(sec==0){ W=pcWs; a=pcAs; proj=projP; colbase=0; }
        else if(sec==1){ W=cpWd; a=cpAd; proj=projP; colbase=4; }
        else if(sec==2){ W=pcWd; a=pcAd; proj=projC; colbase=0; }
        else { W=cpWs; a=cpAs; proj=projC; colbase=4; }
        int k = t >> 2, h = t & 3;
        const float* w = W + (size_t)k*512 + h*128;
        const float* av = a + h*128;
        float s=0.f;
        for(int c=0;c<128;c++) s += w[c]*av[c];
        proj[k*8 + colbase + h] = s;
    } else if(blk == 2056){
        if(tid < 128){
            float s=0.f;
            for(int o=0;o<128;o++) s += lpW[(size_t)tid*128+o]*linkW[o];
            w_p[tid]=s;
        } else {
            int j=tid-128;
            float s=0.f;
            for(int o=0;o<128;o++) s += lcW[(size_t)j*128+o]*linkW[128+o];
            w_c[j]=s;
        }
        if(tid==0){ float s=0.f; for(int o=0;o<128;o++) s+=lpb[o]*linkW[o];      cpc[0]=s; }
        if(tid==1){ float s=0.f; for(int o=0;o<128;o++) s+=lcb[o]*linkW[128+o];  cpc[1]=s; }
    } else {
        int e = (blk-2057)*256 + tid;
        if(e < E){
            atomicAdd(&deg[dst[e]],1);
            atomicAdd(&deg[NCLS + src[e]],1);
        }
    }
}

// ---------- hierarchical exclusive scan ----------
__global__ __launch_bounds__(1024) void scan1(const int* __restrict__ in, int* __restrict__ out,
                                              int* __restrict__ part, int n){
    __shared__ int buf[1024];
    int tid = threadIdx.x;
    int g = blockIdx.x*1024 + tid;
    int v = (g<n) ? in[g] : 0;
    buf[tid] = v;
    __syncthreads();
    for(int o=1;o<1024;o<<=1){
        int t = (tid>=o) ? buf[tid-o] : 0;
        __syncthreads();
        buf[tid] += t;
        __syncthreads();
    }
    if(g<n) out[g] = buf[tid] - v;
    if(tid==1023) part[blockIdx.x] = buf[1023];
}
__global__ __launch_bounds__(64) void scan2(int* __restrict__ part, int nb,
                                            int* __restrict__ offv, int n){
    int tid = threadIdx.x;
    int orig = (tid<nb) ? part[tid] : 0;
    int v = orig;
    #pragma unroll
    for(int o=1;o<64;o<<=1){
        int t = __shfl_up(v, o);
        if(tid>=o) v += t;
    }
    int total = __shfl(v, nb-1);
    if(tid<nb) part[tid] = v - orig;
    if(tid == (n>>10)) offv[n] = total - (v - orig);
}

// ---------- merged SAGE (both types; C1 bf16) ----------
__global__ __launch_bounds__(256) void sage_all(const int* __restrict__ offv, const int* __restrict__ part,
                                                const int* __restrict__ adj,
                                                const unsigned short* __restrict__ P1,
                                                const unsigned short* __restrict__ C1,
                                                const float* __restrict__ bl_pc, const float* __restrict__ bl_cp,
                                                unsigned short* __restrict__ h_c, unsigned short* __restrict__ h_p){
    int v = blockIdx.x*4 + (threadIdx.x>>6);
    int l = threadIdx.x & 63;
    if(v >= SCAN_N) return;
    int b = OFFV(offv,part,v), deg = OFFV(offv,part,v+1)-b;
    float a0=0.f, a1=0.f;
    float inv = 1.f/(float)max(deg,1);
    if(v < NCLS){
        #pragma unroll 4
        for(int i=0;i<deg;i++){
            int s = adj[b+i];
            ushort2 w = *((const ushort2*)P1 + (size_t)s*128 + l);
            a0 += bf2f(w.x); a1 += bf2f(w.y);
        }
        ushort2 sv = *((const ushort2*)C1 + (size_t)v*128 + 64 + l);
        float h0 = fmaxf(a0*inv + bl_pc[2*l]   + bf2f(sv.x), 0.f);
        float h1 = fmaxf(a1*inv + bl_pc[2*l+1] + bf2f(sv.y), 0.f);
        ushort2 o; o.x=f2bf(h0); o.y=f2bf(h1);
        *((ushort2*)h_c + (size_t)v*64 + l) = o;
    } else {
        int m = v - NCLS;
        #pragma unroll 4
        for(int i=0;i<deg;i++){
            int d = adj[b+i];
            ushort2 w = *((const ushort2*)C1 + (size_t)d*128 + l);
            a0 += bf2f(w.x); a1 += bf2f(w.y);
        }
        ushort2 sv = *((const ushort2*)P1 + (size_t)m*128 + 64 + l);
        float h0 = fmaxf(a0*inv + bl_cp[2*l]   + bf2f(sv.x), 0.f);
        float h1 = fmaxf(a1*inv + bl_cp[2*l+1] + bf2f(sv.y), 0.f);
        ushort2 o; o.x=f2bf(h0); o.y=f2bf(h1);
        *((ushort2*)h_p + (size_t)m*64 + l) = o;
    }
}

// ---------- fused GAT v3: ONE WAVE per node, no barriers, no LDS ----------
// lane layout: head h=lane>>4, channel-octet c8=lane&15 (channels c8*8..c8*8+7)
__global__ __launch_bounds__(512) void gat_all(const int* __restrict__ offv, const int* __restrict__ part,
                                               const int* __restrict__ adj,
                                               const float* __restrict__ attP, const float* __restrict__ attC,
                                               const unsigned short* __restrict__ hs_p,
                                               const unsigned short* __restrict__ hs_c,
                                               const float* __restrict__ gb_pc, const float* __restrict__ gb_cp,
                                               const float* __restrict__ w_c, const float* __restrict__ w_p,
                                               const float* __restrict__ cpc,
                                               float* __restrict__ u_c, float* __restrict__ u_p){
    int n = blockIdx.x*8 + (threadIdx.x>>6);
    if(n >= SCAN_N) return;
    const int lane = threadIdx.x & 63;
    const bool cls = n < NCLS;
    const int node = cls ? n : n - NCLS;
    const float* attS = cls ? attP : attC;
    const float* attD = cls ? attC : attP;
    const int abase = cls ? 0 : 4;
    const unsigned short* hs = cls ? hs_p : hs_c;
    const float* gb = cls ? gb_pc : gb_cp;
    const float* wv = cls ? w_c : w_p;
    float* u = cls ? u_c : u_p;
    const int cidx = cls ? 1 : 0;

    const int h  = lane >> 4;     // head
    const int c8 = lane & 15;     // channel octet
    int b = OFFV(offv,part,n), deg = OFFV(offv,part,n+1)-b;
    const float ald_h = attD[(size_t)node*8 + abase + h];

    float acc[8] = {};
    float den = 0.f;

    for(int ii=0; ii<deg; ++ii){
        int s = __builtin_amdgcn_readfirstlane(adj[b+ii]);
        float e = attS[(size_t)s*8 + abase + h] + ald_h;
        e = e > 0.f ? e : 0.2f*e;
        float ee = __expf(e);
        den += ee;                // all 16 lanes of head h accumulate the FULL denominator
        short8 v8 = *(const short8*)(hs + (size_t)s*512 + h*128 + c8*8);
        #pragma unroll
        for(int q=0;q<8;q++) acc[q] += ee * bf2f((unsigned short)v8[q]);
    }

    float inv = (deg > 0) ? 0.25f/den : 0.f;
    #pragma unroll
    for(int q=0;q<8;q++){
        float x = acc[q]*inv;
        x += __shfl_xor(x, 16);   // sum heads 0+1 / 2+3
        x += __shfl_xor(x, 32);   // sum all 4 heads
        acc[q] = x;
    }

    // epilogue: Σ_c relu(out[c]+gb[c])*wv[c]; this lane owns channels c8*8+q
    float val = 0.f;
    #pragma unroll
    for(int q=0;q<8;q++){
        int c = c8*8 + q;
        val += fmaxf(acc[q] + gb[c], 0.f) * wv[c];
    }
    val += __shfl_xor(val, 1);
    val += __shfl_xor(val, 2);
    val += __shfl_xor(val, 4);
    val += __shfl_xor(val, 8);
    if(lane == 0) u[node] = val + cpc[cidx];
}

__global__ void link_out(const int* __restrict__ els, const int* __restrict__ eld,
                         const float* __restrict__ u_p, const float* __restrict__ u_c,
                         const float* __restrict__ linkb, float* __restrict__ out, int EL){
    int i = blockIdx.x*256 + threadIdx.x;
    if(i >= EL) return;
    float x = u_p[els[i]] + u_c[eld[i]] + linkb[0];
    out[i] = 1.f/(1.f + __expf(-x));
}

// ---------- host ----------
extern "C" void kernel_launch(void* const* d_in, const int* in_sizes, int n_in,
                              void* d_out, int out_size, void* d_ws, size_t ws_size,
                              hipStream_t stream){
    const float* x_p  = (const float*)d_in[0];
    const float* x_c  = (const float*)d_in[1];
    const int*   src  = (const int*)d_in[2];
    const int*   dst  = (const int*)d_in[3];
    const int*   els  = (const int*)d_in[4];
    const int*   eld  = (const int*)d_in[5];
    const float* sage_pc_Wl = (const float*)d_in[6];
    const float* sage_pc_bl = (const float*)d_in[7];
    const float* sage_pc_Wr = (const float*)d_in[8];
    const float* sage_cp_Wl = (const float*)d_in[9];
    const float* sage_cp_bl = (const float*)d_in[10];
    const float* sage_cp_Wr = (const float*)d_in[11];
    const float* gat_pc_Wsrc = (const float*)d_in[12];
    const float* gat_pc_Wdst = (const float*)d_in[13];
    const float* gat_pc_asrc = (const float*)d_in[14];
    const float* gat_pc_adst = (const float*)d_in[15];
    const float* gat_pc_b    = (const float*)d_in[16];
    const float* gat_cp_Wsrc = (const float*)d_in[17];
    const float* gat_cp_Wdst = (const float*)d_in[18];
    const float* gat_cp_asrc = (const float*)d_in[19];
    const float* gat_cp_adst = (const float*)d_in[20];
    const float* gat_cp_b    = (const float*)d_in[21];
    const float* lin_p_W = (const float*)d_in[22];
    const float* lin_p_b = (const float*)d_in[23];
    const float* lin_c_W = (const float*)d_in[24];
    const float* lin_c_b = (const float*)d_in[25];
    const float* link_W  = (const float*)d_in[26];
    const float* link_b  = (const float*)d_in[27];

    const int E  = in_sizes[2];
    const int EL = in_sizes[4];

    float* ws = (float*)d_ws;
    size_t off = 0;
    auto alloc = [&](size_t n)->float*{ float* p = ws + off; off += (n + 3) & ~(size_t)3; return p; };

    unsigned short* BtP  = (unsigned short*)alloc((size_t)256*DIMP/2);
    float* WcatC = alloc((size_t)DIMC*256);
    unsigned short* BtSp = (unsigned short*)alloc((size_t)512*128/2);
    unsigned short* BtSc = (unsigned short*)alloc((size_t)512*128/2);
    unsigned short* P1   = (unsigned short*)alloc((size_t)NPROT*256/2);
    unsigned short* C1   = (unsigned short*)alloc((size_t)NCLS*256/2);
    unsigned short* h_p  = (unsigned short*)alloc((size_t)NPROT*128/2);
    unsigned short* h_c  = (unsigned short*)alloc((size_t)NCLS*128/2);
    unsigned short* hs_p = (unsigned short*)alloc((size_t)NPROT*512/2);
    unsigned short* hs_c = (unsigned short*)alloc((size_t)NCLS*512/2);
    float* attP  = alloc((size_t)NPROT*8);
    float* attC  = alloc((size_t)NCLS*8);
    float* projP = alloc(128*8);
    float* projC = alloc(128*8);
    float* w_p   = alloc(128);
    float* w_c   = alloc(128);
    float* cpc   = alloc(4);
    int* degcur = (int*)alloc((size_t)2*SCAN_N);   // deg | cur (one memset)
    int* deg = degcur;
    int* cur = degcur + SCAN_N;
    int* offv = (int*)alloc(SCAN_N+1);
    int* part = (int*)alloc(64);
    int* adj  = (int*)alloc((size_t)2*E);
    float* u_p = alloc(NPROT);
    float* u_c = alloc(NCLS);
    if(off*4 > ws_size) return;

    hipMemsetAsync(degcur, 0, (size_t)2*SCAN_N*4, stream);

    // --- setup: weight prep + folds + degree count ---
    setup<<<2057 + (E+255)/256, 256, 0, stream>>>(
        sage_pc_Wl, sage_cp_Wr, sage_cp_Wl, sage_pc_Wr,
        gat_pc_Wsrc, gat_pc_asrc, gat_pc_Wdst, gat_pc_adst,
        gat_cp_Wsrc, gat_cp_asrc, gat_cp_Wdst, gat_cp_adst,
        lin_p_W, lin_p_b, lin_c_W, lin_c_b, link_W,
        src, dst,
        BtP, WcatC, BtSp, BtSc, projP, projC, w_p, w_c, cpc, deg, E);

    // --- scan ---
    const int NB = (SCAN_N + 1023)/1024;
    scan1<<<NB,1024,0,stream>>>(deg, offv, part, SCAN_N);
    scan2<<<1,64,0,stream>>>(part, NB, offv, SCAN_N);

    // --- mega: gemm64(C1) | csr_fill | gemm_p1 (short branches first) ---
    const int FILLB = (E+511)/512;
    mega1<<<C1B + FILLB + P1B, 512, 0, stream>>>(x_p, BtP, P1, x_c, WcatC, C1,
                                                 src, dst, offv, part, cur, adj, E);

    // --- SAGE ---
    sage_all<<<(SCAN_N+3)/4,256,0,stream>>>(offv, part, adj, P1, C1, sage_pc_bl, sage_cp_bl, h_c, h_p);

    // --- layer 2 GEMM (+ fused att) ---
    gemm_hs<<<dim3(4,NPB+NCB),256,0,stream>>>(h_p, h_c, BtSp, BtSc, projP, projC,
                                              hs_p, hs_c, attP, attC);

    // --- fused GAT + output head (one wave per node) ---
    gat_all<<<(SCAN_N+7)/8,512,0,stream>>>(offv, part, adj, attP, attC, hs_p, hs_c,
                                           gat_pc_b, gat_cp_b, w_c, w_p, cpc, u_c, u_p);

    link_out<<<(EL+255)/256,256,0,stream>>>(els, eld, u_p, u_c, link_b, (float*)d_out, EL);
}